// Round 5
// baseline (5397.600 us; speedup 1.0000x reference)
//
#include <hip/hip_runtime.h>
#include <hip/hip_bf16.h>
#include <stdint.h>

#define BB 4
#define TT 64
#define NN 4096
#define HH 128
#define EE 65536
#define BN (BB*NN)   // 16384

typedef __attribute__((ext_vector_type(8))) short short8;
typedef __attribute__((ext_vector_type(4))) float f32x4;

__device__ __forceinline__ unsigned short bf16r(float f) {
    unsigned u = __float_as_uint(f);
    u += 0x7fffu + ((u >> 16) & 1u);
    return (unsigned short)(u >> 16);
}
__device__ __forceinline__ float bf2f(unsigned bits16) {
    return __uint_as_float(bits16 << 16);
}
__device__ __forceinline__ float sigm(float x) { return 1.f / (1.f + __expf(-x)); }
__device__ __forceinline__ float tanhfast(float x) {
    return 1.f - 2.f / (__expf(2.f * x) + 1.f);
}
// byte address within a [64][128]-bf16 LDS tile, XOR-swizzled
__device__ __forceinline__ unsigned swz(int row, int colbyte) {
    return (unsigned)(row * 256 + (colbyte ^ ((row & 7) << 4)));
}

// ================= packs =================
// WcbP: [half][nt(8)][ks(4)][lane(64)][8].  half0: Wc = W_msg@W_mix[0:128]; half1: W_mix[128:256]
__global__ void pack_wcb_kernel(const float* __restrict__ W_msg, const float* __restrict__ W_mix,
                                short* __restrict__ out)
{
    int idx = blockIdx.x * 256 + threadIdx.x;   // 4096
    if (idx >= 4096) return;
    int l = idx & 63, ks = (idx >> 6) & 3, nt = (idx >> 8) & 7, half = idx >> 11;
    int lo = l & 15, hi = l >> 4;
    int col = nt * 16 + lo;
    short8 v;
    #pragma unroll
    for (int i = 0; i < 8; ++i) {
        int k = ks * 32 + hi * 8 + i;
        float s;
        if (half == 0) {
            s = 0.f;
            for (int j = 0; j < 128; ++j) s += W_msg[k * 128 + j] * W_mix[j * 128 + col];
        } else {
            s = W_mix[(128 + k) * 128 + col];
        }
        v[i] = (short)bf16r(s);
    }
    *(short8*)(out + (size_t)idx * 8) = v;
}

// Wp4: 32 tiles x 8 ks. nt 0-7=r, 8-15=z (ks<4 Wih / ks>=4 Whh), 16-23=i_n (Wih,ks<4), 24-31=h_n (Whh,ks>=4)
__global__ void pack_ihh_kernel(const float* __restrict__ Wih, const float* __restrict__ Whh,
                                short* __restrict__ out)
{
    int idx = blockIdx.x * 256 + threadIdx.x;   // 16384
    if (idx >= 32 * 8 * 64) return;
    int l = idx & 63, ks = (idx >> 6) & 7, nt = idx >> 9;
    int lo = l & 15, hi = l >> 4;
    short8 v;
    #pragma unroll
    for (int i = 0; i < 8; ++i) {
        int k = ks * 32 + hi * 8 + i;
        float s = 0.f;
        if (nt < 16) {
            int col = nt * 16 + lo;
            s = (ks < 4) ? Wih[k * 384 + col] : Whh[(k - 128) * 384 + col];
        } else if (nt < 24) {
            int col = 256 + (nt - 16) * 16 + lo;
            s = (ks < 4) ? Wih[k * 384 + col] : 0.f;
        } else {
            int col = 256 + (nt - 24) * 16 + lo;
            s = (ks >= 4) ? Whh[(k - 128) * 384 + col] : 0.f;
        }
        v[i] = (short)bf16r(s);
    }
    *(short8*)(out + (size_t)idx * 8) = v;
}

__global__ void pack_bias_kernel(const float* __restrict__ b_ih, const float* __restrict__ b_hh,
                                 const float* __restrict__ b_msg, const float* __restrict__ W_mix,
                                 float* __restrict__ biasRZ, float* __restrict__ bvec)
{
    int j = threadIdx.x;
    biasRZ[j]       = b_ih[j]       + b_hh[j];
    biasRZ[128 + j] = b_ih[128 + j] + b_hh[128 + j];
    float s = 0.f;
    for (int jj = 0; jj < 128; ++jj) s += b_msg[jj] * W_mix[jj * 128 + j];
    bvec[j] = s;
}

// ================= the whole-T-loop mega kernel =================
// 256 blocks x 512 threads, 1 block/CU. Block owns 64 rows of one b; runs all 64 steps.
// XCD swizzle: block i -> XCD i%8 (assumed); XCD pair {2b,2b+1} handles batch b so the
// per-step 2MB x-slice stays L2-resident per XCD.
__global__ __launch_bounds__(512, 2)
void mega_kernel(const float* __restrict__ x,
                 const short* __restrict__ WcbP, const short* __restrict__ Wp4,
                 const float* __restrict__ degf,
                 const float* __restrict__ bvec, const float* __restrict__ b_mix,
                 const float* __restrict__ biasRZ,
                 const float* __restrict__ b_ih, const float* __restrict__ b_hh,
                 const float* __restrict__ W_ro, const float* __restrict__ b_ro,
                 const float* __restrict__ targets, const void* __restrict__ maskp,
                 const int* __restrict__ flag,
                 const int* __restrict__ csr_off, const int* __restrict__ csr_src,
                 float* __restrict__ lossBlock)
{
    __shared__ unsigned short aggT[64 * 128];    // swizzled bf16
    __shared__ unsigned short xbT[64 * 128];     // swizzled bf16 (own x rows)
    __shared__ unsigned short miT[64 * 128];     // swizzled bf16
    __shared__ unsigned short stateT[64 * 128];  // swizzled bf16
    __shared__ float pP[8][64];
    __shared__ float sdegS[64];

    const int tid = threadIdx.x;
    const int w = tid >> 6, l = tid & 63, lo = l & 15, hi = l >> 4;
    const int nt = w;
    const int phys = blockIdx.x;
    const int xcd = phys & 7;
    const int b = xcd >> 1;
    const int sub = ((phys >> 3) << 1) | (xcd & 1);   // 0..63
    const int n0 = sub * 64;

    // ---- load all B-fragments into registers, once ----
    short8 wB[8], wR[8], wZ[8], wN[4], wH[4];
    #pragma unroll
    for (int ks = 0; ks < 8; ++ks) {
        wB[ks] = *(const short8*)(WcbP + (size_t)((((ks >> 2) * 8 + nt) * 4 + (ks & 3)) * 64 + l) * 8);
        wR[ks] = *(const short8*)(Wp4 + (size_t)((nt * 8 + ks) * 64 + l) * 8);
        wZ[ks] = *(const short8*)(Wp4 + (size_t)(((8 + nt) * 8 + ks) * 64 + l) * 8);
    }
    #pragma unroll
    for (int ks = 0; ks < 4; ++ks) {
        wN[ks] = *(const short8*)(Wp4 + (size_t)(((16 + nt) * 8 + ks) * 64 + l) * 8);
        wH[ks] = *(const short8*)(Wp4 + (size_t)(((24 + nt) * 8 + (ks + 4)) * 64 + l) * 8);
    }

    const int jcol = nt * 16 + lo;
    const float br = biasRZ[jcol], bz = biasRZ[128 + jcol];
    const float bi = b_ih[256 + jcol], bh = b_hh[256 + jcol];
    const float wro = W_ro[jcol];
    const float bv = bvec[jcol], bm = b_mix[jcol];
    const float bro = b_ro[0];
    const int fl = *flag;

    #pragma unroll
    for (int it = 0; it < 8; ++it)
        ((unsigned*)stateT)[tid + it * 512] = 0u;
    if (tid < 64) sdegS[tid] = degf[n0 + tid];
    float lossAcc = 0.f;
    __syncthreads();

    for (int t = 0; t < TT; ++t) {
        const float* __restrict__ xslab = x + ((size_t)(b * TT + t)) * NN * HH;

        // ---- A1: stage own 64 x-rows -> xbT (bf16) ----
        #pragma unroll
        for (int it = 0; it < 8; ++it) {
            int idx = tid + it * 512;          // 4096 col-pairs
            int row = idx >> 6, cp = idx & 63;
            float2 v = *(const float2*)(xslab + (size_t)(n0 + row) * HH + cp * 2);
            unsigned pk = (unsigned)bf16r(v.x) | ((unsigned)bf16r(v.y) << 16);
            *(unsigned*)((char*)xbT + swz(row, cp * 4)) = pk;
        }
        // ---- A2: gather neighbor x-row sums -> aggT ----
        for (int rr = 0; rr < 8; ++rr) {
            int row = w * 8 + rr;
            int dst = n0 + row;
            int s = csr_off[dst], e = csr_off[dst + 1];
            float a0 = 0.f, a1 = 0.f, c0 = 0.f, c1 = 0.f;
            int i = s;
            for (; i + 1 < e; i += 2) {
                float2 v0 = *(const float2*)(xslab + (size_t)csr_src[i] * HH + l * 2);
                float2 v1 = *(const float2*)(xslab + (size_t)csr_src[i + 1] * HH + l * 2);
                a0 += v0.x; a1 += v0.y; c0 += v1.x; c1 += v1.y;
            }
            if (i < e) {
                float2 v0 = *(const float2*)(xslab + (size_t)csr_src[i] * HH + l * 2);
                a0 += v0.x; a1 += v0.y;
            }
            a0 += c0; a1 += c1;
            *(unsigned*)((char*)aggT + swz(row, l * 4)) =
                (unsigned)bf16r(a0) | ((unsigned)bf16r(a1) << 16);
        }
        __syncthreads();   // bar1

        // ---- B: mi = agg@Wc + state@Wb + deg*bvec + b_mix ----
        f32x4 mAcc[4] = {};
        #pragma unroll
        for (int ks = 0; ks < 8; ++ks) {
            #pragma unroll
            for (int s4 = 0; s4 < 4; ++s4) {
                short8 af = (ks < 4)
                    ? *(const short8*)((const char*)aggT + swz(s4 * 16 + lo, ks * 64 + hi * 16))
                    : *(const short8*)((const char*)stateT + swz(s4 * 16 + lo, (ks - 4) * 64 + hi * 16));
                mAcc[s4] = __builtin_amdgcn_mfma_f32_16x16x32_bf16(af, wB[ks], mAcc[s4], 0, 0, 0);
            }
        }
        #pragma unroll
        for (int s4 = 0; s4 < 4; ++s4)
            #pragma unroll
            for (int q = 0; q < 4; ++q) {
                int row = s4 * 16 + hi * 4 + q;
                float v = mAcc[s4][q] + sdegS[row] * bv + bm;
                *(unsigned short*)((char*)miT + swz(row, jcol * 2)) = bf16r(v);
            }
        __syncthreads();   // bar2

        // ---- C: R/Z (K=256), N (K=128, A=mi), H (K=128, A=xbT) ----
        f32x4 aR[4] = {}, aZ[4] = {}, aN4[4] = {}, aH4[4] = {};
        #pragma unroll
        for (int ks = 0; ks < 8; ++ks) {
            short8 af[4];
            #pragma unroll
            for (int s4 = 0; s4 < 4; ++s4)
                af[s4] = (ks < 4)
                    ? *(const short8*)((const char*)miT + swz(s4 * 16 + lo, ks * 64 + hi * 16))
                    : *(const short8*)((const char*)xbT + swz(s4 * 16 + lo, (ks - 4) * 64 + hi * 16));
            #pragma unroll
            for (int s4 = 0; s4 < 4; ++s4)
                aR[s4] = __builtin_amdgcn_mfma_f32_16x16x32_bf16(af[s4], wR[ks], aR[s4], 0, 0, 0);
            #pragma unroll
            for (int s4 = 0; s4 < 4; ++s4)
                aZ[s4] = __builtin_amdgcn_mfma_f32_16x16x32_bf16(af[s4], wZ[ks], aZ[s4], 0, 0, 0);
            if (ks < 4) {
                #pragma unroll
                for (int s4 = 0; s4 < 4; ++s4)
                    aN4[s4] = __builtin_amdgcn_mfma_f32_16x16x32_bf16(af[s4], wN[ks], aN4[s4], 0, 0, 0);
            } else {
                #pragma unroll
                for (int s4 = 0; s4 < 4; ++s4)
                    aH4[s4] = __builtin_amdgcn_mfma_f32_16x16x32_bf16(af[s4], wH[ks - 4], aH4[s4], 0, 0, 0);
            }
        }

        // ---- D: gates, state (LDS), W_ro partial dot ----
        float pacc[4][4];
        #pragma unroll
        for (int s4 = 0; s4 < 4; ++s4)
            #pragma unroll
            for (int q = 0; q < 4; ++q) {
                int row = s4 * 16 + hi * 4 + q;
                float rg = sigm(aR[s4][q] + br);
                float zg = sigm(aZ[s4][q] + bz);
                float ng = tanhfast(aN4[s4][q] + bi + rg * (aH4[s4][q] + bh));
                float xv = bf2f(*(const unsigned short*)((const char*)xbT + swz(row, jcol * 2)));
                float ns = (1.f - zg) * ng + zg * xv;
                *(unsigned short*)((char*)stateT + swz(row, jcol * 2)) = bf16r(ns);
                pacc[s4][q] = ns * wro;
            }
        #pragma unroll
        for (int o = 1; o < 16; o <<= 1)
            #pragma unroll
            for (int s4 = 0; s4 < 4; ++s4)
                #pragma unroll
                for (int q = 0; q < 4; ++q)
                    pacc[s4][q] += __shfl_xor(pacc[s4][q], o);
        if (lo == 0) {
            #pragma unroll
            for (int s4 = 0; s4 < 4; ++s4)
                #pragma unroll
                for (int q = 0; q < 4; ++q)
                    pP[w][s4 * 16 + hi * 4 + q] = pacc[s4][q];
        }
        __syncthreads();   // bar3

        // ---- loss consume (wave 0) ----
        if (tid < 64) {
            int row = tid;
            float out = bro;
            #pragma unroll
            for (int ww = 0; ww < 8; ++ww) out += pP[ww][row];
            size_t ti = ((size_t)(b * TT + t)) * NN + (n0 + row);
            float tgt = targets[ti];
            float mv = fl ? (((const unsigned char*)maskp)[ti] ? 1.f : 0.f)
                          : (((const int*)maskp)[ti] ? 1.f : 0.f);
            float d = out - tgt;
            lossAcc += 0.5f * d * d * mv;
        }
    }

    if (tid < 64) {
        float v = lossAcc;
        #pragma unroll
        for (int o = 1; o < 64; o <<= 1) v += __shfl_xor(v, o);
        if (tid == 0) lossBlock[phys] = v;
    }
}

// ================= CSR build =================
__global__ void count_kernel(const int* __restrict__ dst, int* __restrict__ counts)
{
    int e = blockIdx.x * 256 + threadIdx.x;
    if (e < EE) atomicAdd(&counts[dst[e]], 1);
}

__global__ __launch_bounds__(1024)
void scan_kernel(const int* __restrict__ counts, int* __restrict__ off, int* __restrict__ cursor,
                 float* __restrict__ degf)
{
    __shared__ int s[1024];
    int tid = threadIdx.x;
    int base = tid * 4;
    int c[4]; int sum = 0;
    #pragma unroll
    for (int i = 0; i < 4; ++i) { c[i] = counts[base + i]; sum += c[i]; }
    s[tid] = sum; __syncthreads();
    for (int o = 1; o < 1024; o <<= 1) {
        int v = (tid >= o) ? s[tid - o] : 0;
        __syncthreads();
        s[tid] += v;
        __syncthreads();
    }
    int incl = s[tid];
    int run = incl - sum;
    #pragma unroll
    for (int i = 0; i < 4; ++i) {
        off[base + i] = run; cursor[base + i] = run;
        degf[base + i] = (float)c[i];
        run += c[i];
    }
    if (tid == 1023) off[4096] = incl;
}

__global__ void fill_kernel(const int* __restrict__ src, const int* __restrict__ dst,
                            int* __restrict__ cursor, int* __restrict__ csr_src)
{
    int e = blockIdx.x * 256 + threadIdx.x;
    if (e < EE) {
        int d = dst[e];
        int pos = atomicAdd(&cursor[d], 1);
        csr_src[pos] = src[e];
    }
}

// ================= mask detect / masked count =================
__global__ void detect_kernel(const unsigned char* __restrict__ maskb, int* __restrict__ flag)
{
    int i = blockIdx.x * 256 + threadIdx.x;
    bool hit = (i < BB * TT * NN) && (i & 3) && maskb[i];
    if (__any(hit) && (threadIdx.x & 63) == 0) atomicOr(flag, 1);
}

__global__ void masksum_kernel(const void* __restrict__ maskp, const int* __restrict__ flag,
                               float* __restrict__ den)
{
    int i = blockIdx.x * 256 + threadIdx.x;
    float v = 0.f;
    if (i < BB * TT * NN) {
        if (*flag) v = ((const unsigned char*)maskp)[i] ? 1.f : 0.f;
        else       v = ((const int*)maskp)[i] ? 1.f : 0.f;
    }
    #pragma unroll
    for (int o = 32; o > 0; o >>= 1) v += __shfl_down(v, o);
    __shared__ float sm[4];
    if ((threadIdx.x & 63) == 0) sm[threadIdx.x >> 6] = v;
    __syncthreads();
    if (threadIdx.x == 0) atomicAdd(den, sm[0] + sm[1] + sm[2] + sm[3]);
}

// ================= final reduce + dual-dtype output =================
__global__ __launch_bounds__(256)
void final_kernel(const float* __restrict__ lossBlock, const float* __restrict__ den,
                  unsigned* __restrict__ out)
{
    __shared__ float s[256];
    s[threadIdx.x] = lossBlock[threadIdx.x];
    __syncthreads();
    for (int o = 128; o > 0; o >>= 1) {
        if (threadIdx.x < o) s[threadIdx.x] += s[threadIdx.x + o];
        __syncthreads();
    }
    if (threadIdx.x == 0) {
        float L = s[0] / den[0];
        unsigned u = __float_as_uint(L);
        u += 0x7fffu + ((u >> 16) & 1u);
        unsigned hi = u >> 16;
        out[0] = hi * 0x10001u;   // bf16-exact low half; ~bf16 value as f32
    }
}

extern "C" void kernel_launch(void* const* d_in, const int* in_sizes, int n_in,
                              void* d_out, int out_size, void* d_ws, size_t ws_size,
                              hipStream_t stream)
{
    const float* x       = (const float*)d_in[0];
    const float* targets = (const float*)d_in[1];
    const float* W_msg   = (const float*)d_in[2];
    const float* b_msg   = (const float*)d_in[3];
    const float* W_mix   = (const float*)d_in[4];
    const float* b_mix   = (const float*)d_in[5];
    const float* W_ih    = (const float*)d_in[6];
    const float* b_ih    = (const float*)d_in[7];
    const float* W_hh    = (const float*)d_in[8];
    const float* b_hh    = (const float*)d_in[9];
    const float* W_ro    = (const float*)d_in[10];
    const float* b_ro    = (const float*)d_in[11];
    const void*  maskp   = d_in[12];
    const int*   esrc    = (const int*)d_in[13];
    const int*   edst    = (const int*)d_in[14];

    char* ws = (char*)d_ws;
    short* WcbP        = (short*)ws; ws += (size_t)4096 * 8 * 2;
    short* Wp4         = (short*)ws; ws += (size_t)32 * 8 * 64 * 8 * 2;
    float* biasRZ      = (float*)ws; ws += 256 * 4;
    float* bvec        = (float*)ws; ws += 128 * 4;
    float* degf        = (float*)ws; ws += 4096 * 4;
    float* lossBlock   = (float*)ws; ws += 256 * 4;
    int*   csr_off     = (int*)ws;   ws += 4104 * 4;
    int*   cursor      = (int*)ws;   ws += 4096 * 4;
    int*   counts      = (int*)ws;   ws += 4096 * 4;
    int*   csr_src     = (int*)ws;   ws += (size_t)EE * 4;
    int*   flag        = (int*)ws;   ws += 64;
    float* den         = (float*)ws; ws += 64;

    hipMemsetAsync(counts, 0, 4096 * 4, stream);
    hipMemsetAsync(flag, 0, 64, stream);
    hipMemsetAsync(den, 0, 4, stream);

    detect_kernel   <<<4096, 256, 0, stream>>>((const unsigned char*)maskp, flag);
    masksum_kernel  <<<4096, 256, 0, stream>>>(maskp, flag, den);
    count_kernel    <<<EE / 256, 256, 0, stream>>>(edst, counts);
    scan_kernel     <<<1, 1024, 0, stream>>>(counts, csr_off, cursor, degf);
    fill_kernel     <<<EE / 256, 256, 0, stream>>>(esrc, edst, cursor, csr_src);
    pack_wcb_kernel <<<16, 256, 0, stream>>>(W_msg, W_mix, WcbP);
    pack_ihh_kernel <<<64, 256, 0, stream>>>(W_ih, W_hh, Wp4);
    pack_bias_kernel<<<1, 128, 0, stream>>>(b_ih, b_hh, b_msg, W_mix, biasRZ, bvec);

    mega_kernel<<<256, 512, 0, stream>>>(x, WcbP, Wp4, degf, bvec, b_mix, biasRZ,
                                         b_ih, b_hh, W_ro, b_ro, targets, maskp, flag,
                                         csr_off, csr_src, lossBlock);
    final_kernel<<<1, 256, 0, stream>>>(lossBlock, den, (unsigned*)d_out);
}

// Round 6
// 2133.739 us; speedup vs baseline: 2.5296x; 2.5296x over previous
//
#include <hip/hip_runtime.h>
#include <hip/hip_bf16.h>
#include <stdint.h>

#define BB 4
#define TT 64
#define NN 4096
#define HH 128
#define EE 65536
#define BN (BB*NN)   // 16384

typedef __attribute__((ext_vector_type(8))) short short8;
typedef __attribute__((ext_vector_type(4))) float f32x4;

__device__ __forceinline__ unsigned short bf16r(float f) {
    unsigned u = __float_as_uint(f);
    u += 0x7fffu + ((u >> 16) & 1u);
    return (unsigned short)(u >> 16);
}
__device__ __forceinline__ float bf2f(unsigned bits16) {
    return __uint_as_float(bits16 << 16);
}
__device__ __forceinline__ float sigm(float x) { return 1.f / (1.f + __expf(-x)); }
__device__ __forceinline__ float tanhfast(float x) {
    return 1.f - 2.f / (__expf(2.f * x) + 1.f);
}
// byte address within a [64][128]-bf16 LDS tile, XOR-swizzled
__device__ __forceinline__ unsigned swz(int row, int colbyte) {
    return (unsigned)(row * 256 + (colbyte ^ ((row & 7) << 4)));
}

// ================= packs =================
// WcbP: [half][nt(8)][ks(4)][lane(64)][8].  half0: Wc = W_msg@W_mix[0:128]; half1: W_mix[128:256]
__global__ void pack_wcb_kernel(const float* __restrict__ W_msg, const float* __restrict__ W_mix,
                                short* __restrict__ out)
{
    int idx = blockIdx.x * 256 + threadIdx.x;   // 4096
    if (idx >= 4096) return;
    int l = idx & 63, ks = (idx >> 6) & 3, nt = (idx >> 8) & 7, half = idx >> 11;
    int lo = l & 15, hi = l >> 4;
    int col = nt * 16 + lo;
    short8 v;
    #pragma unroll
    for (int i = 0; i < 8; ++i) {
        int k = ks * 32 + hi * 8 + i;
        float s;
        if (half == 0) {
            s = 0.f;
            for (int j = 0; j < 128; ++j) s += W_msg[k * 128 + j] * W_mix[j * 128 + col];
        } else {
            s = W_mix[(128 + k) * 128 + col];
        }
        v[i] = (short)bf16r(s);
    }
    *(short8*)(out + (size_t)idx * 8) = v;
}

// Wp4: 32 tiles x 8 ks. nt 0-7=r, 8-15=z (ks<4 Wih / ks>=4 Whh), 16-23=i_n (Wih,ks<4), 24-31=h_n (Whh,ks>=4)
__global__ void pack_ihh_kernel(const float* __restrict__ Wih, const float* __restrict__ Whh,
                                short* __restrict__ out)
{
    int idx = blockIdx.x * 256 + threadIdx.x;   // 16384
    if (idx >= 32 * 8 * 64) return;
    int l = idx & 63, ks = (idx >> 6) & 7, nt = idx >> 9;
    int lo = l & 15, hi = l >> 4;
    short8 v;
    #pragma unroll
    for (int i = 0; i < 8; ++i) {
        int k = ks * 32 + hi * 8 + i;
        float s = 0.f;
        if (nt < 16) {
            int col = nt * 16 + lo;
            s = (ks < 4) ? Wih[k * 384 + col] : Whh[(k - 128) * 384 + col];
        } else if (nt < 24) {
            int col = 256 + (nt - 16) * 16 + lo;
            s = (ks < 4) ? Wih[k * 384 + col] : 0.f;
        } else {
            int col = 256 + (nt - 24) * 16 + lo;
            s = (ks >= 4) ? Whh[(k - 128) * 384 + col] : 0.f;
        }
        v[i] = (short)bf16r(s);
    }
    *(short8*)(out + (size_t)idx * 8) = v;
}

__global__ void pack_bias_kernel(const float* __restrict__ b_ih, const float* __restrict__ b_hh,
                                 const float* __restrict__ b_msg, const float* __restrict__ W_mix,
                                 float* __restrict__ biasRZ, float* __restrict__ bvec)
{
    int j = threadIdx.x;
    biasRZ[j]       = b_ih[j]       + b_hh[j];
    biasRZ[128 + j] = b_ih[128 + j] + b_hh[128 + j];
    float s = 0.f;
    for (int jj = 0; jj < 128; ++jj) s += b_msg[jj] * W_mix[jj * 128 + j];
    bvec[j] = s;
}

// ================= x -> bf16 (all of it, once) =================
__global__ __launch_bounds__(256)
void cvt_all_kernel(const float* __restrict__ src, unsigned short* __restrict__ dst, long nchunk)
{
    long i = (long)blockIdx.x * 256 + threadIdx.x;
    long stride = (long)gridDim.x * 256;
    for (; i < nchunk; i += stride) {
        float4 v = *(const float4*)(src + i * 4);
        ushort4 o;
        o.x = bf16r(v.x); o.y = bf16r(v.y); o.z = bf16r(v.z); o.w = bf16r(v.w);
        *(ushort4*)(dst + i * 4) = o;
    }
}

// ================= gather for ALL (b,t) at once: agg[bt,dst,:] = sum_src xb[bt,src,:] =================
__global__ __launch_bounds__(256)
void gather_all_kernel(const unsigned short* __restrict__ xb,
                       const int* __restrict__ off, const int* __restrict__ srcs,
                       unsigned short* __restrict__ agg)
{
    int rb = blockIdx.x * 4 + (threadIdx.x >> 6);   // 0 .. B*T*N-1
    int l = threadIdx.x & 63;
    int dst = rb & 4095;
    int bt  = rb >> 12;
    const unsigned short* __restrict__ xr = xb + (size_t)bt * NN * HH;
    int s = off[dst], e = off[dst + 1];
    float a0 = 0.f, a1 = 0.f, c0 = 0.f, c1 = 0.f;
    int i = s;
    for (; i + 1 < e; i += 2) {
        unsigned v0 = *(const unsigned*)(xr + (size_t)srcs[i] * HH + l * 2);
        unsigned v1 = *(const unsigned*)(xr + (size_t)srcs[i + 1] * HH + l * 2);
        a0 += bf2f(v0 & 0xffffu); a1 += bf2f(v0 >> 16);
        c0 += bf2f(v1 & 0xffffu); c1 += bf2f(v1 >> 16);
    }
    if (i < e) {
        unsigned v0 = *(const unsigned*)(xr + (size_t)srcs[i] * HH + l * 2);
        a0 += bf2f(v0 & 0xffffu); a1 += bf2f(v0 >> 16);
    }
    a0 += c0; a1 += c1;
    *(unsigned*)(agg + (size_t)rb * HH + l * 2) = (unsigned)bf16r(a0) | ((unsigned)bf16r(a1) << 16);
}

// ================= persistent T-loop kernel (regular streaming only) =================
// 256 blocks x 512 threads, 1 block/CU. Block owns 64 rows of one b; runs all 64 steps.
__global__ __launch_bounds__(512, 2)
void mega2_kernel(const unsigned short* __restrict__ xb,
                  const unsigned short* __restrict__ agg,
                  const short* __restrict__ WcbP, const short* __restrict__ Wp4,
                  const float* __restrict__ degf,
                  const float* __restrict__ bvec, const float* __restrict__ b_mix,
                  const float* __restrict__ biasRZ,
                  const float* __restrict__ b_ih, const float* __restrict__ b_hh,
                  const float* __restrict__ W_ro, const float* __restrict__ b_ro,
                  const float* __restrict__ targets, const void* __restrict__ maskp,
                  const int* __restrict__ flag,
                  float* __restrict__ lossBlock)
{
    __shared__ unsigned short aggT[64 * 128];    // swizzled bf16
    __shared__ unsigned short xbT[64 * 128];     // swizzled bf16
    __shared__ unsigned short miT[64 * 128];     // swizzled bf16
    __shared__ unsigned short stateT[64 * 128];  // swizzled bf16
    __shared__ float pP[8][64];
    __shared__ float sdegS[64];

    const int tid = threadIdx.x;
    const int w = tid >> 6, l = tid & 63, lo = l & 15, hi = l >> 4;
    const int nt = w;
    const int phys = blockIdx.x;
    const int b = phys >> 6;
    const int n0 = (phys & 63) * 64;

    // ---- load all B-fragments into registers, once ----
    short8 wB[8], wR[8], wZ[8], wN[4], wH[4];
    #pragma unroll
    for (int ks = 0; ks < 8; ++ks) {
        wB[ks] = *(const short8*)(WcbP + (size_t)((((ks >> 2) * 8 + nt) * 4 + (ks & 3)) * 64 + l) * 8);
        wR[ks] = *(const short8*)(Wp4 + (size_t)((nt * 8 + ks) * 64 + l) * 8);
        wZ[ks] = *(const short8*)(Wp4 + (size_t)(((8 + nt) * 8 + ks) * 64 + l) * 8);
    }
    #pragma unroll
    for (int ks = 0; ks < 4; ++ks) {
        wN[ks] = *(const short8*)(Wp4 + (size_t)(((16 + nt) * 8 + ks) * 64 + l) * 8);
        wH[ks] = *(const short8*)(Wp4 + (size_t)(((24 + nt) * 8 + (ks + 4)) * 64 + l) * 8);
    }

    const int jcol = nt * 16 + lo;
    const float br = biasRZ[jcol], bz = biasRZ[128 + jcol];
    const float bi = b_ih[256 + jcol], bh = b_hh[256 + jcol];
    const float wro = W_ro[jcol];
    const float bv = bvec[jcol], bm = b_mix[jcol];
    const float bro = b_ro[0];
    const int fl = *flag;

    #pragma unroll
    for (int it = 0; it < 8; ++it)
        ((unsigned*)stateT)[tid + it * 512] = 0u;
    if (tid < 64) sdegS[tid] = degf[n0 + tid];
    float lossAcc = 0.f;
    __syncthreads();

    for (int t = 0; t < TT; ++t) {
        const size_t slab = ((size_t)(b * TT + t)) * NN * HH;

        // ---- A: stage agg & xb rows (coalesced 16B chunks) ----
        #pragma unroll
        for (int it = 0; it < 2; ++it) {
            int idx = tid + it * 512;           // 1024 chunks of 16B per buffer
            int row = idx >> 4, c16 = idx & 15;
            short8 vx = *(const short8*)(xb + slab + (size_t)(n0 + row) * HH + c16 * 8);
            *(short8*)((char*)xbT + swz(row, c16 * 16)) = vx;
            short8 va = *(const short8*)(agg + slab + (size_t)(n0 + row) * HH + c16 * 8);
            *(short8*)((char*)aggT + swz(row, c16 * 16)) = va;
        }
        __syncthreads();   // bar1

        // ---- B: mi = agg@Wc + state@Wb + deg*bvec + b_mix ----
        f32x4 mAcc[4] = {};
        #pragma unroll
        for (int ks = 0; ks < 8; ++ks) {
            #pragma unroll
            for (int s4 = 0; s4 < 4; ++s4) {
                short8 af = (ks < 4)
                    ? *(const short8*)((const char*)aggT + swz(s4 * 16 + lo, ks * 64 + hi * 16))
                    : *(const short8*)((const char*)stateT + swz(s4 * 16 + lo, (ks - 4) * 64 + hi * 16));
                mAcc[s4] = __builtin_amdgcn_mfma_f32_16x16x32_bf16(af, wB[ks], mAcc[s4], 0, 0, 0);
            }
        }
        #pragma unroll
        for (int s4 = 0; s4 < 4; ++s4)
            #pragma unroll
            for (int q = 0; q < 4; ++q) {
                int row = s4 * 16 + hi * 4 + q;
                float v = mAcc[s4][q] + sdegS[row] * bv + bm;
                *(unsigned short*)((char*)miT + swz(row, jcol * 2)) = bf16r(v);
            }
        __syncthreads();   // bar2

        // ---- C: R/Z (K=256), N (K=128, A=mi), H (K=128, A=xbT) ----
        f32x4 aR[4] = {}, aZ[4] = {}, aN4[4] = {}, aH4[4] = {};
        #pragma unroll
        for (int ks = 0; ks < 8; ++ks) {
            short8 af[4];
            #pragma unroll
            for (int s4 = 0; s4 < 4; ++s4)
                af[s4] = (ks < 4)
                    ? *(const short8*)((const char*)miT + swz(s4 * 16 + lo, ks * 64 + hi * 16))
                    : *(const short8*)((const char*)xbT + swz(s4 * 16 + lo, (ks - 4) * 64 + hi * 16));
            #pragma unroll
            for (int s4 = 0; s4 < 4; ++s4)
                aR[s4] = __builtin_amdgcn_mfma_f32_16x16x32_bf16(af[s4], wR[ks], aR[s4], 0, 0, 0);
            #pragma unroll
            for (int s4 = 0; s4 < 4; ++s4)
                aZ[s4] = __builtin_amdgcn_mfma_f32_16x16x32_bf16(af[s4], wZ[ks], aZ[s4], 0, 0, 0);
            if (ks < 4) {
                #pragma unroll
                for (int s4 = 0; s4 < 4; ++s4)
                    aN4[s4] = __builtin_amdgcn_mfma_f32_16x16x32_bf16(af[s4], wN[ks], aN4[s4], 0, 0, 0);
            } else {
                #pragma unroll
                for (int s4 = 0; s4 < 4; ++s4)
                    aH4[s4] = __builtin_amdgcn_mfma_f32_16x16x32_bf16(af[s4], wH[ks - 4], aH4[s4], 0, 0, 0);
            }
        }

        // ---- D: gates, state (LDS), W_ro partial dot ----
        float pacc[4][4];
        #pragma unroll
        for (int s4 = 0; s4 < 4; ++s4)
            #pragma unroll
            for (int q = 0; q < 4; ++q) {
                int row = s4 * 16 + hi * 4 + q;
                float rg = sigm(aR[s4][q] + br);
                float zg = sigm(aZ[s4][q] + bz);
                float ng = tanhfast(aN4[s4][q] + bi + rg * (aH4[s4][q] + bh));
                float xv = bf2f(*(const unsigned short*)((const char*)xbT + swz(row, jcol * 2)));
                float ns = (1.f - zg) * ng + zg * xv;
                *(unsigned short*)((char*)stateT + swz(row, jcol * 2)) = bf16r(ns);
                pacc[s4][q] = ns * wro;
            }
        #pragma unroll
        for (int o = 1; o < 16; o <<= 1)
            #pragma unroll
            for (int s4 = 0; s4 < 4; ++s4)
                #pragma unroll
                for (int q = 0; q < 4; ++q)
                    pacc[s4][q] += __shfl_xor(pacc[s4][q], o);
        if (lo == 0) {
            #pragma unroll
            for (int s4 = 0; s4 < 4; ++s4)
                #pragma unroll
                for (int q = 0; q < 4; ++q)
                    pP[w][s4 * 16 + hi * 4 + q] = pacc[s4][q];
        }
        __syncthreads();   // bar3

        // ---- loss consume (wave 0) ----
        if (tid < 64) {
            int row = tid;
            float out = bro;
            #pragma unroll
            for (int ww = 0; ww < 8; ++ww) out += pP[ww][row];
            size_t ti = ((size_t)(b * TT + t)) * NN + (n0 + row);
            float tgt = targets[ti];
            float mv = fl ? (((const unsigned char*)maskp)[ti] ? 1.f : 0.f)
                          : (((const int*)maskp)[ti] ? 1.f : 0.f);
            float d = out - tgt;
            lossAcc += 0.5f * d * d * mv;
        }
    }

    if (tid < 64) {
        float v = lossAcc;
        #pragma unroll
        for (int o = 1; o < 64; o <<= 1) v += __shfl_xor(v, o);
        if (tid == 0) lossBlock[phys] = v;
    }
}

// ================= CSR build =================
__global__ void count_kernel(const int* __restrict__ dst, int* __restrict__ counts)
{
    int e = blockIdx.x * 256 + threadIdx.x;
    if (e < EE) atomicAdd(&counts[dst[e]], 1);
}

__global__ __launch_bounds__(1024)
void scan_kernel(const int* __restrict__ counts, int* __restrict__ off, int* __restrict__ cursor,
                 float* __restrict__ degf)
{
    __shared__ int s[1024];
    int tid = threadIdx.x;
    int base = tid * 4;
    int c[4]; int sum = 0;
    #pragma unroll
    for (int i = 0; i < 4; ++i) { c[i] = counts[base + i]; sum += c[i]; }
    s[tid] = sum; __syncthreads();
    for (int o = 1; o < 1024; o <<= 1) {
        int v = (tid >= o) ? s[tid - o] : 0;
        __syncthreads();
        s[tid] += v;
        __syncthreads();
    }
    int incl = s[tid];
    int run = incl - sum;
    #pragma unroll
    for (int i = 0; i < 4; ++i) {
        off[base + i] = run; cursor[base + i] = run;
        degf[base + i] = (float)c[i];
        run += c[i];
    }
    if (tid == 1023) off[4096] = incl;
}

__global__ void fill_kernel(const int* __restrict__ src, const int* __restrict__ dst,
                            int* __restrict__ cursor, int* __restrict__ csr_src)
{
    int e = blockIdx.x * 256 + threadIdx.x;
    if (e < EE) {
        int d = dst[e];
        int pos = atomicAdd(&cursor[d], 1);
        csr_src[pos] = src[e];
    }
}

// ================= mask detect / masked count =================
__global__ void detect_kernel(const unsigned char* __restrict__ maskb, int* __restrict__ flag)
{
    int i = blockIdx.x * 256 + threadIdx.x;
    bool hit = (i < BB * TT * NN) && (i & 3) && maskb[i];
    if (__any(hit) && (threadIdx.x & 63) == 0) atomicOr(flag, 1);
}

__global__ void masksum_kernel(const void* __restrict__ maskp, const int* __restrict__ flag,
                               float* __restrict__ den)
{
    int i = blockIdx.x * 256 + threadIdx.x;
    float v = 0.f;
    if (i < BB * TT * NN) {
        if (*flag) v = ((const unsigned char*)maskp)[i] ? 1.f : 0.f;
        else       v = ((const int*)maskp)[i] ? 1.f : 0.f;
    }
    #pragma unroll
    for (int o = 32; o > 0; o >>= 1) v += __shfl_down(v, o);
    __shared__ float sm[4];
    if ((threadIdx.x & 63) == 0) sm[threadIdx.x >> 6] = v;
    __syncthreads();
    if (threadIdx.x == 0) atomicAdd(den, sm[0] + sm[1] + sm[2] + sm[3]);
}

// ================= final reduce + dual-dtype output =================
__global__ __launch_bounds__(256)
void final_kernel(const float* __restrict__ lossBlock, const float* __restrict__ den,
                  unsigned* __restrict__ out)
{
    __shared__ float s[256];
    s[threadIdx.x] = lossBlock[threadIdx.x];
    __syncthreads();
    for (int o = 128; o > 0; o >>= 1) {
        if (threadIdx.x < o) s[threadIdx.x] += s[threadIdx.x + o];
        __syncthreads();
    }
    if (threadIdx.x == 0) {
        float L = s[0] / den[0];
        unsigned u = __float_as_uint(L);
        u += 0x7fffu + ((u >> 16) & 1u);
        unsigned hi = u >> 16;
        out[0] = hi * 0x10001u;   // bf16-exact low half; ~bf16 value as f32
    }
}

extern "C" void kernel_launch(void* const* d_in, const int* in_sizes, int n_in,
                              void* d_out, int out_size, void* d_ws, size_t ws_size,
                              hipStream_t stream)
{
    const float* x       = (const float*)d_in[0];
    const float* targets = (const float*)d_in[1];
    const float* W_msg   = (const float*)d_in[2];
    const float* b_msg   = (const float*)d_in[3];
    const float* W_mix   = (const float*)d_in[4];
    const float* b_mix   = (const float*)d_in[5];
    const float* W_ih    = (const float*)d_in[6];
    const float* b_ih    = (const float*)d_in[7];
    const float* W_hh    = (const float*)d_in[8];
    const float* b_hh    = (const float*)d_in[9];
    const float* W_ro    = (const float*)d_in[10];
    const float* b_ro    = (const float*)d_in[11];
    const void*  maskp   = d_in[12];
    const int*   esrc    = (const int*)d_in[13];
    const int*   edst    = (const int*)d_in[14];

    char* ws = (char*)d_ws;
    unsigned short* xb  = (unsigned short*)ws; ws += (size_t)BB * TT * NN * HH * 2;  // 268 MB
    unsigned short* agg = (unsigned short*)ws; ws += (size_t)BB * TT * NN * HH * 2;  // 268 MB
    short* WcbP        = (short*)ws; ws += (size_t)4096 * 8 * 2;
    short* Wp4         = (short*)ws; ws += (size_t)32 * 8 * 64 * 8 * 2;
    float* biasRZ      = (float*)ws; ws += 256 * 4;
    float* bvec        = (float*)ws; ws += 128 * 4;
    float* degf        = (float*)ws; ws += 4096 * 4;
    float* lossBlock   = (float*)ws; ws += 256 * 4;
    int*   csr_off     = (int*)ws;   ws += 4104 * 4;
    int*   cursor      = (int*)ws;   ws += 4096 * 4;
    int*   counts      = (int*)ws;   ws += 4096 * 4;
    int*   csr_src     = (int*)ws;   ws += (size_t)EE * 4;
    int*   flag        = (int*)ws;   ws += 64;
    float* den         = (float*)ws; ws += 64;

    hipMemsetAsync(counts, 0, 4096 * 4, stream);
    hipMemsetAsync(flag, 0, 64, stream);
    hipMemsetAsync(den, 0, 4, stream);

    detect_kernel   <<<4096, 256, 0, stream>>>((const unsigned char*)maskp, flag);
    masksum_kernel  <<<4096, 256, 0, stream>>>(maskp, flag, den);
    count_kernel    <<<EE / 256, 256, 0, stream>>>(edst, counts);
    scan_kernel     <<<1, 1024, 0, stream>>>(counts, csr_off, cursor, degf);
    fill_kernel     <<<EE / 256, 256, 0, stream>>>(esrc, edst, cursor, csr_src);
    pack_wcb_kernel <<<16, 256, 0, stream>>>(W_msg, W_mix, WcbP);
    pack_ihh_kernel <<<64, 256, 0, stream>>>(W_ih, W_hh, Wp4);
    pack_bias_kernel<<<1, 128, 0, stream>>>(b_ih, b_hh, b_msg, W_mix, biasRZ, bvec);

    cvt_all_kernel  <<<2048, 256, 0, stream>>>(x, xb, (long)BB * TT * NN * HH / 4);
    gather_all_kernel<<<(BB * TT * NN) / 4, 256, 0, stream>>>(xb, csr_off, csr_src, agg);

    mega2_kernel<<<256, 512, 0, stream>>>(xb, agg, WcbP, Wp4, degf, bvec, b_mix, biasRZ,
                                          b_ih, b_hh, W_ro, b_ro, targets, maskp, flag,
                                          lossBlock);
    final_kernel<<<1, 256, 0, stream>>>(lossBlock, den, (unsigned*)d_out);
}